// Round 7
// baseline (6817.180 us; speedup 1.0000x reference)
//
#include <hip/hip_runtime.h>

#define TSTEPS 8192
#define H 51
#define NW 13
#define NT (NW * 64)   // 832 threads

typedef float f4  __attribute__((ext_vector_type(4)));
typedef float v52 __attribute__((ext_vector_type(52)));

__device__ __forceinline__ float sigmoidf_fast(float x) {
    return __builtin_amdgcn_rcpf(1.0f + __expf(-x));
}
__device__ __forceinline__ float tanhf_fast(float x) {
    x = fminf(fmaxf(x, -15.0f), 15.0f);
    float t = __expf(-2.0f * x);
    return (1.0f - t) * __builtin_amdgcn_rcpf(1.0f + t);
}

// R7: R6's wave-specialized pipeline + R4's guaranteed register residency.
// R6 (5.3ms) held 208 weight floats/wave at VGPR=132 -> spilled to scratch,
// reloaded every epoch. Here EVERY wave holds ONE 51-float gate-column
// (proven resident at VGPR=84 in R4). 13 waves, 1 barrier/epoch, depth-4
// pipeline, all buffers double-buffered by step parity:
//   waves 0-3  (Whh1 col g): cell1(e-1) [replicated] -> h1 ; z1 gate(e)
//   waves 4-7  (Wih2 col g): z2a(e-2) = Wih2.h1(e-2)        [raw]
//   waves 8-11 (Whh2 col g): cell2(e-3) [replicated] -> h2 ; u2 gate(e-2)
//   wave 12:                 out(e-4) = Wlin.h2(e-4)+blin   [shuffle reduce]
__global__ __launch_bounds__(NT)
void lstm2_pipe13_kernel(const float* __restrict__ x,
                         const float* __restrict__ Wih1,
                         const float* __restrict__ Whh1,
                         const float* __restrict__ bih1,
                         const float* __restrict__ bhh1,
                         const float* __restrict__ Wih2,
                         const float* __restrict__ Whh2,
                         const float* __restrict__ bih2,
                         const float* __restrict__ bhh2,
                         const float* __restrict__ Wlin,
                         const float* __restrict__ blin,
                         float* __restrict__ out)
{
    __shared__ __align__(16) float sh_x[TSTEPS];      // staged input
    __shared__ __align__(16) float sh_out[TSTEPS];    // staged output
    __shared__ __align__(16) float sh_h1[2][64];      // h1, parity = step&1
    __shared__ __align__(16) float sh_h2[2][64];      // h2
    __shared__ __align__(16) float sh_a1[2][256];     // activated L1 gates [unit*4+g]
    __shared__ __align__(16) float sh_z2a[2][256];    // raw Wih2.h1 [unit*4+g]
    __shared__ __align__(16) float sh_u2[2][256];     // raw b2+Whh2.h2 [unit*4+g]

    const int tid  = threadIdx.x;
    const int wave = tid >> 6;
    const int lane = tid & 63;
    const int row  = (lane < H) ? lane : (H - 1);     // clamp for weight loads

    // ---- stage x (coalesced f4) ----
    for (int i = tid; i < TSTEPS / 4; i += NT)
        ((f4*)sh_x)[i] = ((const f4*)x)[i];

    // ---- per-wave single gate-column, register-resident ----
    const int grp  = wave >> 2;                       // 0:L1 1:z2a 2:u2 3:out
    const int gate = wave & 3;
    v52 w;
    float bias = 0.0f, wx = 0.0f;
    if (grp < 3) {
        const float* M = (grp == 0) ? Whh1 : (grp == 1) ? Wih2 : Whh2;
        const int r = gate * H + row;
#pragma unroll
        for (int k = 0; k < H; ++k) w[k] = M[r * H + k];
        w[51] = 0.0f;
        if (grp == 0) { bias = bih1[r] + bhh1[r]; wx = Wih1[r]; }
        if (grp == 2) { bias = bih2[r] + bhh2[r]; }
    }
    const float wlin = (lane < H) ? Wlin[lane] : 0.0f;
    const float bl   = blin[0];

    // ---- init LDS state ----
    if (tid < 64) {
        sh_h1[0][tid] = 0.0f; sh_h1[1][tid] = 0.0f;
        sh_h2[0][tid] = 0.0f; sh_h2[1][tid] = 0.0f;
    }
    float c1 = 0.0f, c2 = 0.0f;   // replicated cell state (waves 0-3 / 8-11)
    __syncthreads();

#pragma unroll 1
    for (int e = 0; e < TSTEPS + 4; ++e) {
        if (grp == 0) {
            // ---- cell1 for step e-1 (replicated in waves 0-3) ----
            if (e >= 1 && e <= TSTEPS) {
                const int s = e - 1;
                const f4 a = ((const f4*)sh_a1[s & 1])[lane];   // i,f,g,o activated
                c1 = fmaf(a[1], c1, a[0] * a[2]);
                const float h1n = (lane < H) ? a[3] * tanhf_fast(c1) : 0.0f;
                sh_h1[s & 1][lane] = h1n;
            }
            // ---- z1 gate for step e (reads own just-written h1(e-1)) ----
            if (e < TSTEPS) {
                const f4* hv = (const f4*)sh_h1[(e - 1) & 1];   // e=0: parity1 zeros
                float z0 = fmaf(wx, sh_x[e], bias), z1 = 0.0f, z2 = 0.0f, z3 = 0.0f;
#pragma unroll
                for (int p = 0; p < 13; ++p) {
                    const f4 hc = hv[p];
                    z0 = fmaf(w[4*p+0], hc[0], z0);
                    z1 = fmaf(w[4*p+1], hc[1], z1);
                    z2 = fmaf(w[4*p+2], hc[2], z2);
                    z3 = fmaf(w[4*p+3], hc[3], z3);
                }
                const float z = (z0 + z1) + (z2 + z3);
                const float a = (gate == 2) ? tanhf_fast(z) : sigmoidf_fast(z);
                sh_a1[e & 1][lane * 4 + gate] = a;
            }
        } else if (grp == 1) {
            // ---- z2a gate for step e-2 ----
            if (e >= 2 && e < TSTEPS + 2) {
                const int s = e - 2;
                const f4* hv = (const f4*)sh_h1[s & 1];          // written epoch s+1
                float z0 = 0.0f, z1 = 0.0f, z2 = 0.0f, z3 = 0.0f;
#pragma unroll
                for (int p = 0; p < 13; ++p) {
                    const f4 hc = hv[p];
                    z0 = fmaf(w[4*p+0], hc[0], z0);
                    z1 = fmaf(w[4*p+1], hc[1], z1);
                    z2 = fmaf(w[4*p+2], hc[2], z2);
                    z3 = fmaf(w[4*p+3], hc[3], z3);
                }
                sh_z2a[s & 1][lane * 4 + gate] = (z0 + z1) + (z2 + z3);
            }
        } else if (grp == 2) {
            // ---- cell2 for step e-3 (replicated in waves 8-11) ----
            if (e >= 3 && e < TSTEPS + 3) {
                const int s = e - 3;
                const f4 za = ((const f4*)sh_z2a[s & 1])[lane];
                const f4 ua = ((const f4*)sh_u2[s & 1])[lane];
                const float ig = sigmoidf_fast(za[0] + ua[0]);
                const float fg = sigmoidf_fast(za[1] + ua[1]);
                const float gg = tanhf_fast   (za[2] + ua[2]);
                const float og = sigmoidf_fast(za[3] + ua[3]);
                c2 = fmaf(fg, c2, ig * gg);
                const float h2n = (lane < H) ? og * tanhf_fast(c2) : 0.0f;
                sh_h2[s & 1][lane] = h2n;
            }
            // ---- u2 gate for step e-2 (reads own just-written h2(e-3)) ----
            if (e >= 2 && e < TSTEPS + 2) {
                const int s = e - 2;
                const f4* hv = (const f4*)sh_h2[(s - 1) & 1];    // e=2: parity1 zeros
                float z0 = bias, z1 = 0.0f, z2 = 0.0f, z3 = 0.0f;
#pragma unroll
                for (int p = 0; p < 13; ++p) {
                    const f4 hc = hv[p];
                    z0 = fmaf(w[4*p+0], hc[0], z0);
                    z1 = fmaf(w[4*p+1], hc[1], z1);
                    z2 = fmaf(w[4*p+2], hc[2], z2);
                    z3 = fmaf(w[4*p+3], hc[3], z3);
                }
                sh_u2[s & 1][lane * 4 + gate] = (z0 + z1) + (z2 + z3);
            }
        } else {
            // ---- wave 12: out(e-4), off the critical path ----
            if (e >= 4) {
                const int s = e - 4;
                const float hv = sh_h2[s & 1][lane];             // written epoch s+3
                float p = hv * wlin;
                p += __shfl_down(p, 32);
                p += __shfl_down(p, 16);
                p += __shfl_down(p, 8);
                p += __shfl_down(p, 4);
                p += __shfl_down(p, 2);
                p += __shfl_down(p, 1);
                if (lane == 0) sh_out[s] = p + bl;
            }
        }
        __syncthreads();
    }

    // ---- bulk coalesced output store ----
    for (int i = tid; i < TSTEPS / 4; i += NT)
        ((f4*)out)[i] = ((const f4*)sh_out)[i];
}

extern "C" void kernel_launch(void* const* d_in, const int* in_sizes, int n_in,
                              void* d_out, int out_size, void* d_ws, size_t ws_size,
                              hipStream_t stream) {
    const float* x    = (const float*)d_in[0];
    const float* Wih1 = (const float*)d_in[1];
    const float* Whh1 = (const float*)d_in[2];
    const float* bih1 = (const float*)d_in[3];
    const float* bhh1 = (const float*)d_in[4];
    const float* Wih2 = (const float*)d_in[5];
    const float* Whh2 = (const float*)d_in[6];
    const float* bih2 = (const float*)d_in[7];
    const float* bhh2 = (const float*)d_in[8];
    const float* Wlin = (const float*)d_in[9];
    const float* blin = (const float*)d_in[10];
    float* out = (float*)d_out;

    lstm2_pipe13_kernel<<<1, NT, 0, stream>>>(
        x, Wih1, Whh1, bih1, bhh1, Wih2, Whh2, bih2, bhh2, Wlin, blin, out);
}

// Round 8
// 5688.025 us; speedup vs baseline: 1.1985x; 1.1985x over previous
//
#include <hip/hip_runtime.h>

#define TSTEPS 8192
#define H 51
#define NW 12
#define NT (NW * 64)   // 768 threads

typedef float f2 __attribute__((ext_vector_type(2)));
typedef float f4 __attribute__((ext_vector_type(4)));

__device__ __forceinline__ float sigmoidf_fast(float x) {
    return __builtin_amdgcn_rcpf(1.0f + __expf(-x));
}
__device__ __forceinline__ float tanhf_fast(float x) {
    x = fminf(fmaxf(x, -15.0f), 15.0f);
    float t = __expf(-2.0f * x);
    return (1.0f - t) * __builtin_amdgcn_rcpf(1.0f + t);
}
// packed-fp32-friendly dot step
__device__ __forceinline__ void dacc(const f4 w, const f4 h, f2& a0, f2& a1) {
    const f2 wl = __builtin_shufflevector(w, w, 0, 1);
    const f2 wh = __builtin_shufflevector(w, w, 2, 3);
    const f2 hl = __builtin_shufflevector(h, h, 0, 1);
    const f2 hh = __builtin_shufflevector(h, h, 2, 3);
    a0 = __builtin_elementwise_fma(wl, hl, a0);
    a1 = __builtin_elementwise_fma(wh, hh, a1);
}
// Force-pin: "+v" tied operand = value is "modified" -> cannot be remat'd
// from memory, must live in VGPRs across the loop. (R6 spilled at 208 floats;
// R7's 52 floats were silently re-loaded from global every epoch: VGPR=44.)
#define PIN(v) asm volatile("" : "+v"(v))

// R8: R7 pipeline + coerced register residency + shorter chains.
//   waves 0-3  (Whh1 col g): cell1(e-1) repl -> h1 lane-local; z1 gate(e)
//   waves 4-7  (Wih2 col g): z2a(e-2); wave4 also out(e-4) [off-path]
//   waves 8-11 (Whh2 col g): cell2(e-3) repl -> h2 lane-local; u2(e-2)
// Own-wave LDS h-copies are single-buffered (write->read same epoch, lgkm-
// ordered within wave); cross-wave buffers double-buffered by step parity.
// 1 barrier/epoch, depth-4 pipeline, zero global ops in the loop.
__global__ __launch_bounds__(NT)
void lstm2_pin_kernel(const float* __restrict__ x,
                      const float* __restrict__ Wih1,
                      const float* __restrict__ Whh1,
                      const float* __restrict__ bih1,
                      const float* __restrict__ bhh1,
                      const float* __restrict__ Wih2,
                      const float* __restrict__ Whh2,
                      const float* __restrict__ bih2,
                      const float* __restrict__ bhh2,
                      const float* __restrict__ Wlin,
                      const float* __restrict__ blin,
                      float* __restrict__ out)
{
    __shared__ __align__(16) float sh_x[TSTEPS];
    __shared__ __align__(16) float sh_out[TSTEPS];
    __shared__ __align__(16) float sh_a1[2][256];     // activated L1 gates [unit*4+g]
    __shared__ __align__(16) float sh_z2a[2][256];    // raw Wih2.h1
    __shared__ __align__(16) float sh_u2[2][256];     // raw b2+Whh2.h2
    __shared__ __align__(16) float sh_h1own[4][64];   // per-L1-wave h1 copy
    __shared__ __align__(16) float sh_h2own[4][64];   // per-cell2-wave h2 copy
    __shared__ __align__(16) float sh_h1x[2][64];     // shared h1 (wave0 -> grp1)
    __shared__ __align__(16) float sh_h2x[2][64];     // shared h2 (wave8 -> out)

    const int tid  = threadIdx.x;
    const int wave = tid >> 6;
    const int lane = tid & 63;
    const int grp  = wave >> 2;                       // 0:L1 1:z2a(+out) 2:cell2+u2
    const int gate = wave & 3;
    const int row  = (lane < H) ? lane : (H - 1);

    // ---- stage x (coalesced) ----
    for (int i = tid; i < TSTEPS / 4; i += NT)
        ((f4*)sh_x)[i] = ((const f4*)x)[i];

    // ---- one gate-column per wave: 13 named f4s (52 floats) ----
    const float* M = (grp == 0) ? Whh1 : (grp == 1) ? Wih2 : Whh2;
    const float* p = M + (gate * H + row) * H;
    f4 w0, w1, w2, w3, w4, w5, w6, w7, w8, w9, w10, w11, w12;
#define LD4(i) { const int b = 4*i; \
    w##i[0] = p[b]; w##i[1] = p[b+1]; w##i[2] = p[b+2]; \
    w##i[3] = (b + 3 < H) ? p[b+3] : 0.0f; }
    LD4(0) LD4(1) LD4(2) LD4(3) LD4(4) LD4(5) LD4(6)
    LD4(7) LD4(8) LD4(9) LD4(10) LD4(11) LD4(12)
#undef LD4
    float bias = 0.0f, wx = 0.0f;
    if (grp == 0) { bias = bih1[gate * H + row] + bhh1[gate * H + row]; wx = Wih1[gate * H + row]; }
    if (grp == 2) { bias = bih2[gate * H + row] + bhh2[gate * H + row]; }
    const float wlin = (lane < H) ? Wlin[lane] : 0.0f;
    const float bl   = blin[0];

    // ---- init LDS ----
    if (tid < 256) {
        sh_a1[0][tid] = 0.0f; sh_a1[1][tid] = 0.0f;
        sh_z2a[0][tid] = 0.0f; sh_z2a[1][tid] = 0.0f;
        sh_u2[0][tid] = 0.0f; sh_u2[1][tid] = 0.0f;
        sh_h1own[0][tid & 63] = 0.0f;  // covered below anyway
    }
    if (tid < 64) {
        sh_h1own[0][tid] = 0.0f; sh_h1own[1][tid] = 0.0f;
        sh_h1own[2][tid] = 0.0f; sh_h1own[3][tid] = 0.0f;
        sh_h2own[0][tid] = 0.0f; sh_h2own[1][tid] = 0.0f;
        sh_h2own[2][tid] = 0.0f; sh_h2own[3][tid] = 0.0f;
        sh_h1x[0][tid] = 0.0f; sh_h1x[1][tid] = 0.0f;
        sh_h2x[0][tid] = 0.0f; sh_h2x[1][tid] = 0.0f;
    }
    float c1 = 0.0f, c2 = 0.0f;
    __syncthreads();

#define DOT13(HV, A0, A1) \
    dacc(w0,(HV)[0],A0,A1);  dacc(w1,(HV)[1],A0,A1);  dacc(w2,(HV)[2],A0,A1); \
    dacc(w3,(HV)[3],A0,A1);  dacc(w4,(HV)[4],A0,A1);  dacc(w5,(HV)[5],A0,A1); \
    dacc(w6,(HV)[6],A0,A1);  dacc(w7,(HV)[7],A0,A1);  dacc(w8,(HV)[8],A0,A1); \
    dacc(w9,(HV)[9],A0,A1);  dacc(w10,(HV)[10],A0,A1); dacc(w11,(HV)[11],A0,A1); \
    dacc(w12,(HV)[12],A0,A1);

#pragma unroll 1
    for (int e = 0; e < TSTEPS + 4; ++e) {
        PIN(w0); PIN(w1); PIN(w2); PIN(w3); PIN(w4); PIN(w5); PIN(w6);
        PIN(w7); PIN(w8); PIN(w9); PIN(w10); PIN(w11); PIN(w12);

        if (grp == 0) {
            // cell1 for step s=e-1 (replicated; h1 stays lane-local)
            if (e >= 1 && e <= TSTEPS) {
                const int s = e - 1;
                const f4 a = ((const f4*)sh_a1[s & 1])[lane];   // activated i,f,g,o
                c1 = fmaf(a[1], c1, a[0] * a[2]);
                const float h1n = (lane < H) ? a[3] * tanhf_fast(c1) : 0.0f;
                sh_h1own[wave][lane] = h1n;                     // own copy, single-buffered
                if (wave == 0) sh_h1x[s & 1][lane] = h1n;       // shared for grp1
            }
            // z1 gate for step e (reads own just-written h1(e-1))
            if (e < TSTEPS) {
                const f4* hv = (const f4*)sh_h1own[wave];
                f2 a0 = {0.0f, 0.0f}, a1 = {0.0f, 0.0f};
                DOT13(hv, a0, a1)
                float z = (a0[0] + a0[1]) + (a1[0] + a1[1]);
                z += fmaf(wx, sh_x[e], bias);
                const float act = (gate == 2) ? tanhf_fast(z) : sigmoidf_fast(z);
                sh_a1[e & 1][lane * 4 + gate] = act;
            }
        } else if (grp == 1) {
            // z2a gate for step s=e-2
            if (e >= 2 && e < TSTEPS + 2) {
                const int s = e - 2;
                const f4* hv = (const f4*)sh_h1x[s & 1];        // written epoch s+1
                f2 a0 = {0.0f, 0.0f}, a1 = {0.0f, 0.0f};
                DOT13(hv, a0, a1)
                sh_z2a[s & 1][lane * 4 + gate] = (a0[0] + a0[1]) + (a1[0] + a1[1]);
            }
            // wave4: output dot for step s=e-4 (fully off the critical path)
            if (wave == 4 && e >= 4) {
                const int s = e - 4;
                const float hvv = sh_h2x[s & 1][lane];          // written epoch s+3
                float pr = hvv * wlin;
                pr += __shfl_down(pr, 32);
                pr += __shfl_down(pr, 16);
                pr += __shfl_down(pr, 8);
                pr += __shfl_down(pr, 4);
                pr += __shfl_down(pr, 2);
                pr += __shfl_down(pr, 1);
                if (lane == 0) sh_out[s] = pr + bl;
            }
        } else {
            // cell2 for step s=e-3 (replicated; h2 lane-local)
            if (e >= 3 && e < TSTEPS + 3) {
                const int s = e - 3;
                const f4 za = ((const f4*)sh_z2a[s & 1])[lane]; // written epoch s+2
                const f4 ua = ((const f4*)sh_u2[s & 1])[lane];  // written epoch s+2
                const float ig = sigmoidf_fast(za[0] + ua[0]);
                const float fg = sigmoidf_fast(za[1] + ua[1]);
                const float gg = tanhf_fast   (za[2] + ua[2]);
                const float og = sigmoidf_fast(za[3] + ua[3]);
                c2 = fmaf(fg, c2, ig * gg);
                const float h2n = (lane < H) ? og * tanhf_fast(c2) : 0.0f;
                sh_h2own[wave - 8][lane] = h2n;                 // own copy
                if (wave == 8) sh_h2x[s & 1][lane] = h2n;       // shared for out
            }
            // u2 gate for step s2=e-2, uses h2(e-3) just computed
            if (e >= 2 && e < TSTEPS + 2) {
                const int s2 = e - 2;
                const f4* hv = (const f4*)sh_h2own[wave - 8];
                f2 a0 = {0.0f, 0.0f}, a1 = {0.0f, 0.0f};
                DOT13(hv, a0, a1)
                sh_u2[s2 & 1][lane * 4 + gate] =
                    bias + (a0[0] + a0[1]) + (a1[0] + a1[1]);
            }
        }
        __syncthreads();
    }

    // ---- bulk coalesced output store ----
    for (int i = tid; i < TSTEPS / 4; i += NT)
        ((f4*)out)[i] = ((const f4*)sh_out)[i];
}

extern "C" void kernel_launch(void* const* d_in, const int* in_sizes, int n_in,
                              void* d_out, int out_size, void* d_ws, size_t ws_size,
                              hipStream_t stream) {
    const float* x    = (const float*)d_in[0];
    const float* Wih1 = (const float*)d_in[1];
    const float* Whh1 = (const float*)d_in[2];
    const float* bih1 = (const float*)d_in[3];
    const float* bhh1 = (const float*)d_in[4];
    const float* Wih2 = (const float*)d_in[5];
    const float* Whh2 = (const float*)d_in[6];
    const float* bih2 = (const float*)d_in[7];
    const float* bhh2 = (const float*)d_in[8];
    const float* Wlin = (const float*)d_in[9];
    const float* blin = (const float*)d_in[10];
    float* out = (float*)d_out;

    lstm2_pin_kernel<<<1, NT, 0, stream>>>(
        x, Wih1, Whh1, bih1, bhh1, Wih2, Whh2, bih2, bhh2, Wlin, blin, out);
}